// Round 3
// baseline (142.817 us; speedup 1.0000x reference)
//
#include <hip/hip_runtime.h>
#include <hip/hip_bf16.h>

#define CCH 256
#define MM  32768

typedef float    f32x4  __attribute__((ext_vector_type(4)));
typedef _Float16 f16x8  __attribute__((ext_vector_type(8)));
typedef short    bf16x8 __attribute__((ext_vector_type(8)));

__device__ inline unsigned short f2bf(float f) {
  union { float f; unsigned int u; } v; v.f = f;
  unsigned int u = v.u;
  unsigned int r = (u + 0x7fffu + ((u >> 16) & 1u)) >> 16;
  return (unsigned short)r;
}

// ---------------------------------------------------------------------------
// K1: split-K Gram  G_partial = X_chunk * X_chunk^T  (fp16 two-term split)
// ---------------------------------------------------------------------------
__global__ __launch_bounds__(512) void gram_kernel(const float* __restrict__ x,
    float* __restrict__ gpart, float* __restrict__ spart, int Mc, int spb) {
  __shared__ _Float16 hiL[CCH * 32];
  __shared__ _Float16 loL[CCH * 32];
  const int t = threadIdx.x;
  const int b = blockIdx.x;
  const int n = b / spb, ks = b % spb;
  const float* X = x + (size_t)n * CCH * MM + (size_t)ks * Mc;
  const int c = t >> 1, mo = (t & 1) << 4;
  const float* px = X + (size_t)c * MM + mo;
  const int stages = Mc >> 5;
  const int l = t & 63, w = t >> 6;
  const int i0 = w << 1;

  f32x4 acc[2][16];
  #pragma unroll
  for (int ii = 0; ii < 2; ++ii)
    #pragma unroll
    for (int jt = 0; jt < 16; ++jt)
      acc[ii][jt] = (f32x4){0.f, 0.f, 0.f, 0.f};

  float4 p0 = *(const float4*)(px + 0);
  float4 p1 = *(const float4*)(px + 4);
  float4 p2 = *(const float4*)(px + 8);
  float4 p3 = *(const float4*)(px + 12);
  float ssum = 0.f;

  const int kb0 = (t & 1) * 2;
  const int sw  = (c >> 1) & 3;
  _Float16* hd0 = &hiL[c * 32 + ((kb0 + 0) ^ sw) * 8];
  _Float16* hd1 = &hiL[c * 32 + ((kb0 + 1) ^ sw) * 8];
  _Float16* ld0 = &loL[c * 32 + ((kb0 + 0) ^ sw) * 8];
  _Float16* ld1 = &loL[c * 32 + ((kb0 + 1) ^ sw) * 8];

  for (int s = 0; s < stages; ++s) {
    float fv[16];
    fv[0] = p0.x; fv[1] = p0.y; fv[2]  = p0.z; fv[3]  = p0.w;
    fv[4] = p1.x; fv[5] = p1.y; fv[6]  = p1.z; fv[7]  = p1.w;
    fv[8] = p2.x; fv[9] = p2.y; fv[10] = p2.z; fv[11] = p2.w;
    fv[12] = p3.x; fv[13] = p3.y; fv[14] = p3.z; fv[15] = p3.w;
    f16x8 h0, h1, lo0, lo1;
    #pragma unroll
    for (int e = 0; e < 8; ++e) {
      float a = fv[e]; ssum += a;
      _Float16 hh = (_Float16)a;
      h0[e] = hh; lo0[e] = (_Float16)(a - (float)hh);
    }
    #pragma unroll
    for (int e = 0; e < 8; ++e) {
      float a = fv[8 + e]; ssum += a;
      _Float16 hh = (_Float16)a;
      h1[e] = hh; lo1[e] = (_Float16)(a - (float)hh);
    }
    *(f16x8*)hd0 = h0;  *(f16x8*)hd1 = h1;
    *(f16x8*)ld0 = lo0; *(f16x8*)ld1 = lo1;
    if (s + 1 < stages) {
      const float* pn = px + (size_t)(s + 1) * 32;
      p0 = *(const float4*)(pn + 0);
      p1 = *(const float4*)(pn + 4);
      p2 = *(const float4*)(pn + 8);
      p3 = *(const float4*)(pn + 12);
    }
    __syncthreads();
    f16x8 Ahi[2], Alo[2];
    #pragma unroll
    for (int ii = 0; ii < 2; ++ii) {
      int cr = (i0 + ii) * 16 + (l & 15);
      int sl = (l >> 4) ^ ((cr >> 1) & 3);
      int idx = cr * 32 + sl * 8;
      Ahi[ii] = *(const f16x8*)&hiL[idx];
      Alo[ii] = *(const f16x8*)&loL[idx];
    }
    #pragma unroll
    for (int jt = 0; jt < 16; ++jt) {
      int cr = jt * 16 + (l & 15);
      int sl = (l >> 4) ^ ((cr >> 1) & 3);
      int idx = cr * 32 + sl * 8;
      f16x8 Bhi = *(const f16x8*)&hiL[idx];
      f16x8 Blo = *(const f16x8*)&loL[idx];
      #pragma unroll
      for (int ii = 0; ii < 2; ++ii) {
        acc[ii][jt] = __builtin_amdgcn_mfma_f32_16x16x32_f16(Ahi[ii], Bhi, acc[ii][jt], 0, 0, 0);
        acc[ii][jt] = __builtin_amdgcn_mfma_f32_16x16x32_f16(Ahi[ii], Blo, acc[ii][jt], 0, 0, 0);
        acc[ii][jt] = __builtin_amdgcn_mfma_f32_16x16x32_f16(Alo[ii], Bhi, acc[ii][jt], 0, 0, 0);
      }
    }
    __syncthreads();
  }
  float* gp = gpart + ((size_t)n * spb + ks) * 65536;
  #pragma unroll
  for (int ii = 0; ii < 2; ++ii)
    #pragma unroll
    for (int jt = 0; jt < 16; ++jt) {
      int col = jt * 16 + (l & 15);
      int rb  = (i0 + ii) * 16 + ((l >> 4) << 2);
      #pragma unroll
      for (int r = 0; r < 4; ++r)
        gp[(rb + r) * 256 + col] = acc[ii][jt][r];
    }
  ssum += __shfl_xor(ssum, 1);
  if ((t & 1) == 0) spart[((size_t)n * spb + ks) * 256 + c] = ssum;
}

// ---------------------------------------------------------------------------
// K1b: reduce split-K partials -> G (2x256x256), s (2x256); also WkT.
// ---------------------------------------------------------------------------
__global__ __launch_bounds__(256) void reduce_kernel(const float* __restrict__ gpart,
    const float* __restrict__ spart, const float* __restrict__ Wk,
    float* __restrict__ G, float* __restrict__ sv, float* __restrict__ WkT,
    int spb) {
  const int b = blockIdx.x, t = threadIdx.x;
  if (b < 512) {
    int idx = b * 256 + t;
    int n = idx >> 16, e = idx & 65535;
    const float* p = gpart + (size_t)n * spb * 65536 + e;
    float s = 0.f;
    for (int k = 0; k < spb; ++k) s += p[(size_t)k * 65536];
    G[idx] = s;
  } else if (b < 514) {
    int r = (b - 512) * 256 + t;
    int n = r >> 8, cc = r & 255;
    const float* p = spart + (size_t)n * spb * 256 + cc;
    float s = 0.f;
    for (int k = 0; k < spb; ++k) s += p[k * 256];
    sv[r] = s;
  } else {
    int c = b - 514;
    WkT[c * 256 + t] = Wk[t * 256 + c];
  }
}

// ---------------------------------------------------------------------------
// K2a: T1[n][j][t] = sum_c Wq[j][c]*G[n][c][t];  z2[n][j] = wq_j . s_n
// grid = 2*64 blocks (JG=4 rows), 256 threads; reduction operands via s_load.
// ---------------------------------------------------------------------------
__global__ __launch_bounds__(256) void t1_kernel(const float* __restrict__ G,
    const float* __restrict__ sv_g, const float* __restrict__ Wq,
    float* __restrict__ T1, float* __restrict__ z2g) {
  __shared__ float redz[4][4];
  const int t = threadIdx.x, b = blockIdx.x;
  const int n = b >> 6, j0 = (b & 63) << 2;
  const int l = t & 63, w = t >> 6;
  const float* Gn  = G + (size_t)n * 65536;
  const float* wq0 = Wq + (size_t)j0 * 256;
  float a0 = 0.f, a1 = 0.f, a2 = 0.f, a3 = 0.f;
  #pragma unroll 16
  for (int cc = 0; cc < 256; ++cc) {
    float g = Gn[cc * 256 + t];            // coalesced vector load
    a0 += wq0[cc]       * g;               // s_load (uniform)
    a1 += wq0[256 + cc] * g;
    a2 += wq0[512 + cc] * g;
    a3 += wq0[768 + cc] * g;
  }
  float* T1b = T1 + ((size_t)(n * 256 + j0)) * 256;
  T1b[t]       = a0;
  T1b[256 + t] = a1;
  T1b[512 + t] = a2;
  T1b[768 + t] = a3;
  // z2[j] = wq_j . s  (lane-parallel dot + block reduce)
  float s_t = sv_g[n * 256 + t];
  float p0 = wq0[t]       * s_t;
  float p1 = wq0[256 + t] * s_t;
  float p2 = wq0[512 + t] * s_t;
  float p3 = wq0[768 + t] * s_t;
  #pragma unroll
  for (int o = 1; o < 64; o <<= 1) {
    p0 += __shfl_xor(p0, o); p1 += __shfl_xor(p1, o);
    p2 += __shfl_xor(p2, o); p3 += __shfl_xor(p3, o);
  }
  if (l == 0) { redz[w][0] = p0; redz[w][1] = p1; redz[w][2] = p2; redz[w][3] = p3; }
  __syncthreads();
  if (t < 4)
    z2g[n * 256 + j0 + t] = redz[0][t] + redz[1][t] + redz[2][t] + redz[3][t];
}

// ---------------------------------------------------------------------------
// K2b: S[j][t] = sum_c T1[j][c]*WkT[c][t] + bq[j]*(Wk s)[t] + (z2[j]+M bq[j])*bk[t]
//      softmax rows -> att (fp32, ws), bb[j] = att_j . bv
// ---------------------------------------------------------------------------
__global__ __launch_bounds__(256) void s_kernel(const float* __restrict__ T1,
    const float* __restrict__ z2g, const float* __restrict__ sv_g,
    const float* __restrict__ WkT, const float* __restrict__ bq,
    const float* __restrict__ bk, const float* __restrict__ bv,
    float* __restrict__ att, float* __restrict__ bb) {
  __shared__ float redA[4][4], redB[4][4], redC[4][4];
  const int t = threadIdx.x, b = blockIdx.x;
  const int n = b >> 6, j0 = (b & 63) << 2;
  const int l = t & 63, w = t >> 6;
  const float* t1b = T1 + ((size_t)(n * 256 + j0)) * 256;
  const float* sn  = sv_g + n * 256;
  float a0 = 0.f, a1 = 0.f, a2 = 0.f, a3 = 0.f, aa = 0.f;
  #pragma unroll 16
  for (int cc = 0; cc < 256; ++cc) {
    float k = WkT[cc * 256 + t];           // coalesced vector load
    a0 += t1b[cc]       * k;               // s_load
    a1 += t1b[256 + cc] * k;
    a2 += t1b[512 + cc] * k;
    a3 += t1b[768 + cc] * k;
    aa += sn[cc]        * k;               // s_load
  }
  const float bq0 = bq[j0], bq1 = bq[j0 + 1], bq2 = bq[j0 + 2], bq3 = bq[j0 + 3];
  const float z0 = z2g[n * 256 + j0],     z1 = z2g[n * 256 + j0 + 1];
  const float z2v = z2g[n * 256 + j0 + 2], z3 = z2g[n * 256 + j0 + 3];
  const float bkt = bk[t];
  float S0 = a0 + bq0 * aa + (z0 + 32768.0f * bq0) * bkt;
  float S1 = a1 + bq1 * aa + (z1 + 32768.0f * bq1) * bkt;
  float S2 = a2 + bq2 * aa + (z2v + 32768.0f * bq2) * bkt;
  float S3 = a3 + bq3 * aa + (z3 + 32768.0f * bq3) * bkt;
  // row max
  float m0 = S0, m1 = S1, m2 = S2, m3 = S3;
  #pragma unroll
  for (int o = 1; o < 64; o <<= 1) {
    m0 = fmaxf(m0, __shfl_xor(m0, o)); m1 = fmaxf(m1, __shfl_xor(m1, o));
    m2 = fmaxf(m2, __shfl_xor(m2, o)); m3 = fmaxf(m3, __shfl_xor(m3, o));
  }
  if (l == 0) { redA[w][0] = m0; redA[w][1] = m1; redA[w][2] = m2; redA[w][3] = m3; }
  __syncthreads();
  m0 = fmaxf(fmaxf(redA[0][0], redA[1][0]), fmaxf(redA[2][0], redA[3][0]));
  m1 = fmaxf(fmaxf(redA[0][1], redA[1][1]), fmaxf(redA[2][1], redA[3][1]));
  m2 = fmaxf(fmaxf(redA[0][2], redA[1][2]), fmaxf(redA[2][2], redA[3][2]));
  m3 = fmaxf(fmaxf(redA[0][3], redA[1][3]), fmaxf(redA[2][3], redA[3][3]));
  float e0 = expf(S0 - m0), e1 = expf(S1 - m1), e2 = expf(S2 - m2), e3 = expf(S3 - m3);
  float q0 = e0, q1 = e1, q2 = e2, q3 = e3;
  #pragma unroll
  for (int o = 1; o < 64; o <<= 1) {
    q0 += __shfl_xor(q0, o); q1 += __shfl_xor(q1, o);
    q2 += __shfl_xor(q2, o); q3 += __shfl_xor(q3, o);
  }
  if (l == 0) { redB[w][0] = q0; redB[w][1] = q1; redB[w][2] = q2; redB[w][3] = q3; }
  __syncthreads();
  float i0 = 1.0f / (redB[0][0] + redB[1][0] + redB[2][0] + redB[3][0]);
  float i1 = 1.0f / (redB[0][1] + redB[1][1] + redB[2][1] + redB[3][1]);
  float i2 = 1.0f / (redB[0][2] + redB[1][2] + redB[2][2] + redB[3][2]);
  float i3 = 1.0f / (redB[0][3] + redB[1][3] + redB[2][3] + redB[3][3]);
  float at0 = e0 * i0, at1 = e1 * i1, at2 = e2 * i2, at3 = e3 * i3;
  float* ab = att + ((size_t)(n * 256 + j0)) * 256;
  ab[t]       = at0;
  ab[256 + t] = at1;
  ab[512 + t] = at2;
  ab[768 + t] = at3;
  // bb[j] = att_j . bv
  float bvt = bv[t];
  float c0 = at0 * bvt, c1 = at1 * bvt, c2 = at2 * bvt, c3 = at3 * bvt;
  #pragma unroll
  for (int o = 1; o < 64; o <<= 1) {
    c0 += __shfl_xor(c0, o); c1 += __shfl_xor(c1, o);
    c2 += __shfl_xor(c2, o); c3 += __shfl_xor(c3, o);
  }
  if (l == 0) { redC[w][0] = c0; redC[w][1] = c1; redC[w][2] = c2; redC[w][3] = c3; }
  __syncthreads();
  if (t < 4)
    bb[n * 256 + j0 + t] = redC[0][t] + redC[1][t] + redC[2][t] + redC[3][t];
}

// ---------------------------------------------------------------------------
// K2c: Bm[j][t] = sum_c att[j][c] * Wv[c][t]  (bf16 out)
// ---------------------------------------------------------------------------
__global__ __launch_bounds__(256) void bm_kernel(const float* __restrict__ att,
    const float* __restrict__ Wv, unsigned short* __restrict__ Bm) {
  const int t = threadIdx.x, b = blockIdx.x;
  const int n = b >> 6, j0 = (b & 63) << 2;
  const float* ab = att + ((size_t)(n * 256 + j0)) * 256;
  float v0 = 0.f, v1 = 0.f, v2 = 0.f, v3 = 0.f;
  #pragma unroll 16
  for (int cc = 0; cc < 256; ++cc) {
    float wv = Wv[cc * 256 + t];           // coalesced vector load
    v0 += ab[cc]       * wv;               // s_load
    v1 += ab[256 + cc] * wv;
    v2 += ab[512 + cc] * wv;
    v3 += ab[768 + cc] * wv;
  }
  unsigned short* bmb = Bm + ((size_t)(n * 256 + j0)) * 256;
  bmb[t]       = f2bf(v0);
  bmb[256 + t] = f2bf(v1);
  bmb[512 + t] = f2bf(v2);
  bmb[768 + t] = f2bf(v3);
}

// ---------------------------------------------------------------------------
// K3: out[n][m][j] = sum_c Bmat[j][c] * X[c][m] + bb[j]   (bf16 MFMA)
// ---------------------------------------------------------------------------
__global__ __launch_bounds__(256) void out_kernel(const float* __restrict__ x,
    const unsigned short* __restrict__ Bm, const float* __restrict__ bb,
    float* __restrict__ out) {
  __shared__ unsigned short Bl[256 * 64];
  const int t = threadIdx.x;
  const int b = blockIdx.x;
  const int n = b >> 9, mb = b & 511;
  const int m0 = mb << 6;
  const int l = t & 63, w = t >> 6;
  f32x4 acc[16];
  #pragma unroll
  for (int jt = 0; jt < 16; ++jt) acc[jt] = (f32x4){0.f, 0.f, 0.f, 0.f};
  const unsigned short* Bmn = Bm + (size_t)n * 65536;
  const float* xn = x + (size_t)n * CCH * MM;
  const int mA = m0 + w * 16 + (l & 15);
  for (int ch = 0; ch < 4; ++ch) {
    #pragma unroll
    for (int it = 0; it < 8; ++it) {
      int i = it * 256 + t;
      int j = i >> 3, cb = i & 7;
      uint4 v = *(const uint4*)(Bmn + (size_t)j * 256 + ch * 64 + cb * 8);
      int slot = cb ^ (j & 7);
      *(uint4*)&Bl[j * 64 + slot * 8] = v;
    }
    __syncthreads();
    #pragma unroll
    for (int kk = 0; kk < 2; ++kk) {
      int cbase = ch * 64 + kk * 32 + (l >> 4) * 8;
      const float* xp = xn + (size_t)cbase * MM + mA;
      bf16x8 afrag;
      #pragma unroll
      for (int jj = 0; jj < 8; ++jj) {
        float v = xp[(size_t)jj * MM];
        afrag[jj] = (short)f2bf(v);
      }
      int cb2 = kk * 4 + (l >> 4);
      #pragma unroll
      for (int jt = 0; jt < 16; ++jt) {
        int jrow = jt * 16 + (l & 15);
        int slot = cb2 ^ (jrow & 7);
        bf16x8 bfrag = *(const bf16x8*)&Bl[jrow * 64 + slot * 8];
        acc[jt] = __builtin_amdgcn_mfma_f32_16x16x32_bf16(afrag, bfrag, acc[jt], 0, 0, 0);
      }
    }
    __syncthreads();
  }
  float* op = out + (size_t)n * MM * 256;
  const int mrb = m0 + w * 16 + ((l >> 4) << 2);
  #pragma unroll
  for (int jt = 0; jt < 16; ++jt) {
    int jcol = jt * 16 + (l & 15);
    float bias = bb[n * 256 + jcol];
    #pragma unroll
    for (int r = 0; r < 4; ++r)
      op[(size_t)(mrb + r) * 256 + jcol] = acc[jt][r] + bias;
  }
}

// ---------------------------------------------------------------------------
extern "C" void kernel_launch(void* const* d_in, const int* in_sizes, int n_in,
                              void* d_out, int out_size, void* d_ws, size_t ws_size,
                              hipStream_t stream) {
  (void)in_sizes; (void)n_in; (void)out_size;
  const float* x  = (const float*)d_in[0];
  const float* Wq = (const float*)d_in[1];
  const float* bq = (const float*)d_in[2];
  const float* Wk = (const float*)d_in[3];
  const float* bk = (const float*)d_in[4];
  const float* Wv = (const float*)d_in[5];
  const float* bv = (const float*)d_in[6];
  float* out = (float*)d_out;

  int spb = 128;
  while (spb > 1) {
    size_t need = ((size_t)2 * spb * (65536 + 256) + 2 * 65536 + 512 + 512 + 65536) * 4
                + (size_t)2 * 65536 * 2;
    if (need <= ws_size) break;
    spb >>= 1;
  }
  float* wsf   = (float*)d_ws;
  float* gpart = wsf;
  float* spart = gpart + (size_t)2 * spb * 65536;
  float* G     = spart + (size_t)2 * spb * 256;
  float* sv    = G + 2 * 65536;
  float* bb    = sv + 512;
  float* WkT   = bb + 512;
  unsigned short* Bm = (unsigned short*)(WkT + 65536);
  // T1 / z2 / att alias the gpart region (gpart is dead after reduce_kernel,
  // and is fully rewritten by gram_kernel at the start of every launch).
  float* T1  = wsf;                       // 2*256*256 = 131072 floats
  float* z2  = wsf + 131072;              // 512 floats
  float* att = wsf + 131072 + 512;        // 2*256*256 = 131072 floats
  const int Mc = MM / spb;

  gram_kernel<<<dim3(2 * spb), dim3(512), 0, stream>>>(x, gpart, spart, Mc, spb);
  reduce_kernel<<<dim3(770), dim3(256), 0, stream>>>(gpart, spart, Wk, G, sv, WkT, spb);
  t1_kernel<<<dim3(128), dim3(256), 0, stream>>>(G, sv, Wq, T1, z2);
  s_kernel<<<dim3(128), dim3(256), 0, stream>>>(T1, z2, sv, WkT, bq, bk, bv, att, bb);
  bm_kernel<<<dim3(128), dim3(256), 0, stream>>>(att, Wv, Bm);
  out_kernel<<<dim3(1024), dim3(256), 0, stream>>>(x, Bm, bb, out);
}

// Round 4
// 120.148 us; speedup vs baseline: 1.1887x; 1.1887x over previous
//
#include <hip/hip_runtime.h>
#include <hip/hip_bf16.h>

#define CCH 256
#define MM  32768

typedef float    f32x4  __attribute__((ext_vector_type(4)));
typedef _Float16 f16x8  __attribute__((ext_vector_type(8)));
typedef short    bf16x8 __attribute__((ext_vector_type(8)));

__device__ inline unsigned short f2bf(float f) {
  union { float f; unsigned int u; } v; v.f = f;
  unsigned int u = v.u;
  unsigned int r = (u + 0x7fffu + ((u >> 16) & 1u)) >> 16;
  return (unsigned short)r;
}

// ---------------------------------------------------------------------------
// K1: split-K Gram  G_partial = X_chunk * X_chunk^T  (fp16 two-term split)
// ---------------------------------------------------------------------------
__global__ __launch_bounds__(512) void gram_kernel(const float* __restrict__ x,
    float* __restrict__ gpart, float* __restrict__ spart, int Mc, int spb) {
  __shared__ _Float16 hiL[CCH * 32];
  __shared__ _Float16 loL[CCH * 32];
  const int t = threadIdx.x;
  const int b = blockIdx.x;
  const int n = b / spb, ks = b % spb;
  const float* X = x + (size_t)n * CCH * MM + (size_t)ks * Mc;
  const int c = t >> 1, mo = (t & 1) << 4;
  const float* px = X + (size_t)c * MM + mo;
  const int stages = Mc >> 5;
  const int l = t & 63, w = t >> 6;
  const int i0 = w << 1;

  f32x4 acc[2][16];
  #pragma unroll
  for (int ii = 0; ii < 2; ++ii)
    #pragma unroll
    for (int jt = 0; jt < 16; ++jt)
      acc[ii][jt] = (f32x4){0.f, 0.f, 0.f, 0.f};

  float4 p0 = *(const float4*)(px + 0);
  float4 p1 = *(const float4*)(px + 4);
  float4 p2 = *(const float4*)(px + 8);
  float4 p3 = *(const float4*)(px + 12);
  float ssum = 0.f;

  const int kb0 = (t & 1) * 2;
  const int sw  = (c >> 1) & 3;
  _Float16* hd0 = &hiL[c * 32 + ((kb0 + 0) ^ sw) * 8];
  _Float16* hd1 = &hiL[c * 32 + ((kb0 + 1) ^ sw) * 8];
  _Float16* ld0 = &loL[c * 32 + ((kb0 + 0) ^ sw) * 8];
  _Float16* ld1 = &loL[c * 32 + ((kb0 + 1) ^ sw) * 8];

  for (int s = 0; s < stages; ++s) {
    float fv[16];
    fv[0] = p0.x; fv[1] = p0.y; fv[2]  = p0.z; fv[3]  = p0.w;
    fv[4] = p1.x; fv[5] = p1.y; fv[6]  = p1.z; fv[7]  = p1.w;
    fv[8] = p2.x; fv[9] = p2.y; fv[10] = p2.z; fv[11] = p2.w;
    fv[12] = p3.x; fv[13] = p3.y; fv[14] = p3.z; fv[15] = p3.w;
    f16x8 h0, h1, lo0, lo1;
    #pragma unroll
    for (int e = 0; e < 8; ++e) {
      float a = fv[e]; ssum += a;
      _Float16 hh = (_Float16)a;
      h0[e] = hh; lo0[e] = (_Float16)(a - (float)hh);
    }
    #pragma unroll
    for (int e = 0; e < 8; ++e) {
      float a = fv[8 + e]; ssum += a;
      _Float16 hh = (_Float16)a;
      h1[e] = hh; lo1[e] = (_Float16)(a - (float)hh);
    }
    *(f16x8*)hd0 = h0;  *(f16x8*)hd1 = h1;
    *(f16x8*)ld0 = lo0; *(f16x8*)ld1 = lo1;
    if (s + 1 < stages) {
      const float* pn = px + (size_t)(s + 1) * 32;
      p0 = *(const float4*)(pn + 0);
      p1 = *(const float4*)(pn + 4);
      p2 = *(const float4*)(pn + 8);
      p3 = *(const float4*)(pn + 12);
    }
    __syncthreads();
    f16x8 Ahi[2], Alo[2];
    #pragma unroll
    for (int ii = 0; ii < 2; ++ii) {
      int cr = (i0 + ii) * 16 + (l & 15);
      int sl = (l >> 4) ^ ((cr >> 1) & 3);
      int idx = cr * 32 + sl * 8;
      Ahi[ii] = *(const f16x8*)&hiL[idx];
      Alo[ii] = *(const f16x8*)&loL[idx];
    }
    #pragma unroll
    for (int jt = 0; jt < 16; ++jt) {
      int cr = jt * 16 + (l & 15);
      int sl = (l >> 4) ^ ((cr >> 1) & 3);
      int idx = cr * 32 + sl * 8;
      f16x8 Bhi = *(const f16x8*)&hiL[idx];
      f16x8 Blo = *(const f16x8*)&loL[idx];
      #pragma unroll
      for (int ii = 0; ii < 2; ++ii) {
        acc[ii][jt] = __builtin_amdgcn_mfma_f32_16x16x32_f16(Ahi[ii], Bhi, acc[ii][jt], 0, 0, 0);
        acc[ii][jt] = __builtin_amdgcn_mfma_f32_16x16x32_f16(Ahi[ii], Blo, acc[ii][jt], 0, 0, 0);
        acc[ii][jt] = __builtin_amdgcn_mfma_f32_16x16x32_f16(Alo[ii], Bhi, acc[ii][jt], 0, 0, 0);
      }
    }
    __syncthreads();
  }
  float* gp = gpart + ((size_t)n * spb + ks) * 65536;
  #pragma unroll
  for (int ii = 0; ii < 2; ++ii)
    #pragma unroll
    for (int jt = 0; jt < 16; ++jt) {
      int col = jt * 16 + (l & 15);
      int rb  = (i0 + ii) * 16 + ((l >> 4) << 2);
      #pragma unroll
      for (int r = 0; r < 4; ++r)
        gp[(rb + r) * 256 + col] = acc[ii][jt][r];
    }
  ssum += __shfl_xor(ssum, 1);
  if ((t & 1) == 0) spart[((size_t)n * spb + ks) * 256 + c] = ssum;
}

// ---------------------------------------------------------------------------
// K1b: reduce split-K partials -> G (2x256x256), s (2x256); also WkT.
// ---------------------------------------------------------------------------
__global__ __launch_bounds__(256) void reduce_kernel(const float* __restrict__ gpart,
    const float* __restrict__ spart, const float* __restrict__ Wk,
    float* __restrict__ G, float* __restrict__ sv, float* __restrict__ WkT,
    int spb) {
  const int b = blockIdx.x, t = threadIdx.x;
  if (b < 512) {
    int idx = b * 256 + t;
    int n = idx >> 16, e = idx & 65535;
    const float* p = gpart + (size_t)n * spb * 65536 + e;
    float s = 0.f;
    for (int k = 0; k < spb; ++k) s += p[(size_t)k * 65536];
    G[idx] = s;
  } else if (b < 514) {
    int r = (b - 512) * 256 + t;
    int n = r >> 8, cc = r & 255;
    const float* p = spart + (size_t)n * spb * 256 + cc;
    float s = 0.f;
    for (int k = 0; k < spb; ++k) s += p[k * 256];
    sv[r] = s;
  } else {
    int c = b - 514;
    WkT[c * 256 + t] = Wk[t * 256 + c];
  }
}

// ---------------------------------------------------------------------------
// K2 (fused chain): per block = 2 rows (j0, j0+1) of one batch n.
//   phase1: T1[r][t] = sum_c wq[r][c]*G[c][t]         (wq in LDS, b128 bcast)
//   phase2: S[r][t]  = sum_c T1[r][c]*WkT[c][t] + bq*aa + (z2 + M*bq)*bk[t]
//   softmax rows -> att (LDS), bb
//   phase3: Bm[r][t] = sum_c att[r][c]*Wv[c][t]       (bf16)
// All B-side loads coalesced dwords (1KB-stride imm offsets); all A-side from
// LDS as broadcast float4. No scalar-load streams in hot loops.
// grid = 256 blocks x 256 threads.
// ---------------------------------------------------------------------------
__global__ __launch_bounds__(256) void chain_kernel(const float* __restrict__ G,
    const float* __restrict__ sv_g, const float* __restrict__ WkT,
    const float* __restrict__ Wq, const float* __restrict__ bq,
    const float* __restrict__ bk, const float* __restrict__ bv,
    const float* __restrict__ Wv,
    unsigned short* __restrict__ Bm, float* __restrict__ bb) {
  __shared__ float wqL[2][256], sL[256], t1L[2][256], attL[2][256];
  __shared__ float red[4][2];
  const int t = threadIdx.x;
  const int l = t & 63, w = t >> 6;
  const int n = blockIdx.x >> 7;
  const int j0 = (blockIdx.x & 127) << 1;
  const float* Gn = G + (size_t)n * 65536;

  // stage A-side vectors
  wqL[0][t] = Wq[(size_t)j0 * 256 + t];
  wqL[1][t] = Wq[(size_t)(j0 + 1) * 256 + t];
  sL[t]     = sv_g[n * 256 + t];
  __syncthreads();

  // z2[r] = wq_r . s
  float p0 = wqL[0][t] * sL[t];
  float p1 = wqL[1][t] * sL[t];
  #pragma unroll
  for (int o = 1; o < 64; o <<= 1) { p0 += __shfl_xor(p0, o); p1 += __shfl_xor(p1, o); }
  if (l == 0) { red[w][0] = p0; red[w][1] = p1; }
  __syncthreads();
  const float z2_0 = red[0][0] + red[1][0] + red[2][0] + red[3][0];
  const float z2_1 = red[0][1] + red[1][1] + red[2][1] + red[3][1];

  // phase 1: T1 rows
  float a0 = 0.f, a1 = 0.f;
  #pragma unroll 4
  for (int c = 0; c < 256; c += 4) {
    float4 w0 = *(const float4*)&wqL[0][c];
    float4 w1 = *(const float4*)&wqL[1][c];
    const float* gp = Gn + (size_t)c * 256 + t;
    float g0 = gp[0], g1 = gp[256], g2 = gp[512], g3 = gp[768];
    a0 += w0.x * g0 + w0.y * g1 + w0.z * g2 + w0.w * g3;
    a1 += w1.x * g0 + w1.y * g1 + w1.z * g2 + w1.w * g3;
  }
  t1L[0][t] = a0;
  t1L[1][t] = a1;
  __syncthreads();

  // phase 2: S rows
  float b0 = 0.f, b1 = 0.f, aa = 0.f;
  #pragma unroll 4
  for (int c = 0; c < 256; c += 4) {
    float4 t10 = *(const float4*)&t1L[0][c];
    float4 t11 = *(const float4*)&t1L[1][c];
    float4 s4  = *(const float4*)&sL[c];
    const float* kp = WkT + (size_t)c * 256 + t;
    float k0 = kp[0], k1 = kp[256], k2 = kp[512], k3 = kp[768];
    b0 += t10.x * k0 + t10.y * k1 + t10.z * k2 + t10.w * k3;
    b1 += t11.x * k0 + t11.y * k1 + t11.z * k2 + t11.w * k3;
    aa += s4.x  * k0 + s4.y  * k1 + s4.z  * k2 + s4.w  * k3;
  }
  const float bq0 = bq[j0], bq1 = bq[j0 + 1];
  const float bkt = bk[t];
  float S0 = b0 + bq0 * aa + (z2_0 + 32768.0f * bq0) * bkt;
  float S1 = b1 + bq1 * aa + (z2_1 + 32768.0f * bq1) * bkt;

  // softmax over t (rows j0, j0+1)
  float m0 = S0, m1 = S1;
  #pragma unroll
  for (int o = 1; o < 64; o <<= 1) {
    m0 = fmaxf(m0, __shfl_xor(m0, o)); m1 = fmaxf(m1, __shfl_xor(m1, o));
  }
  __syncthreads();                       // protect red from z2 phase readers
  if (l == 0) { red[w][0] = m0; red[w][1] = m1; }
  __syncthreads();
  m0 = fmaxf(fmaxf(red[0][0], red[1][0]), fmaxf(red[2][0], red[3][0]));
  m1 = fmaxf(fmaxf(red[0][1], red[1][1]), fmaxf(red[2][1], red[3][1]));
  float e0 = expf(S0 - m0), e1 = expf(S1 - m1);
  float q0 = e0, q1 = e1;
  #pragma unroll
  for (int o = 1; o < 64; o <<= 1) { q0 += __shfl_xor(q0, o); q1 += __shfl_xor(q1, o); }
  __syncthreads();
  if (l == 0) { red[w][0] = q0; red[w][1] = q1; }
  __syncthreads();
  const float i0 = 1.0f / (red[0][0] + red[1][0] + red[2][0] + red[3][0]);
  const float i1 = 1.0f / (red[0][1] + red[1][1] + red[2][1] + red[3][1]);
  const float at0 = e0 * i0, at1 = e1 * i1;
  attL[0][t] = at0;
  attL[1][t] = at1;

  // bb[r] = att_r . bv
  const float bvt = bv[t];
  float c0 = at0 * bvt, c1 = at1 * bvt;
  #pragma unroll
  for (int o = 1; o < 64; o <<= 1) { c0 += __shfl_xor(c0, o); c1 += __shfl_xor(c1, o); }
  __syncthreads();
  if (l == 0) { red[w][0] = c0; red[w][1] = c1; }
  __syncthreads();                       // also makes attL visible
  if (t < 2) bb[n * 256 + j0 + t] = red[0][t] + red[1][t] + red[2][t] + red[3][t];

  // phase 3: Bm rows
  float v0 = 0.f, v1 = 0.f;
  #pragma unroll 4
  for (int c = 0; c < 256; c += 4) {
    float4 A0 = *(const float4*)&attL[0][c];
    float4 A1 = *(const float4*)&attL[1][c];
    const float* vp = Wv + (size_t)c * 256 + t;
    float x0 = vp[0], x1 = vp[256], x2 = vp[512], x3 = vp[768];
    v0 += A0.x * x0 + A0.y * x1 + A0.z * x2 + A0.w * x3;
    v1 += A1.x * x0 + A1.y * x1 + A1.z * x2 + A1.w * x3;
  }
  unsigned short* bmb = Bm + ((size_t)(n * 256 + j0)) * 256;
  bmb[t]       = f2bf(v0);
  bmb[256 + t] = f2bf(v1);
}

// ---------------------------------------------------------------------------
// K3: out[n][m][j] = sum_c Bmat[j][c] * X[c][m] + bb[j]   (bf16 MFMA)
// ---------------------------------------------------------------------------
__global__ __launch_bounds__(256) void out_kernel(const float* __restrict__ x,
    const unsigned short* __restrict__ Bm, const float* __restrict__ bb,
    float* __restrict__ out) {
  __shared__ unsigned short Bl[256 * 64];
  const int t = threadIdx.x;
  const int b = blockIdx.x;
  const int n = b >> 9, mb = b & 511;
  const int m0 = mb << 6;
  const int l = t & 63, w = t >> 6;
  f32x4 acc[16];
  #pragma unroll
  for (int jt = 0; jt < 16; ++jt) acc[jt] = (f32x4){0.f, 0.f, 0.f, 0.f};
  const unsigned short* Bmn = Bm + (size_t)n * 65536;
  const float* xn = x + (size_t)n * CCH * MM;
  const int mA = m0 + w * 16 + (l & 15);
  for (int ch = 0; ch < 4; ++ch) {
    #pragma unroll
    for (int it = 0; it < 8; ++it) {
      int i = it * 256 + t;
      int j = i >> 3, cb = i & 7;
      uint4 v = *(const uint4*)(Bmn + (size_t)j * 256 + ch * 64 + cb * 8);
      int slot = cb ^ (j & 7);
      *(uint4*)&Bl[j * 64 + slot * 8] = v;
    }
    __syncthreads();
    #pragma unroll
    for (int kk = 0; kk < 2; ++kk) {
      int cbase = ch * 64 + kk * 32 + (l >> 4) * 8;
      const float* xp = xn + (size_t)cbase * MM + mA;
      bf16x8 afrag;
      #pragma unroll
      for (int jj = 0; jj < 8; ++jj) {
        float v = xp[(size_t)jj * MM];
        afrag[jj] = (short)f2bf(v);
      }
      int cb2 = kk * 4 + (l >> 4);
      #pragma unroll
      for (int jt = 0; jt < 16; ++jt) {
        int jrow = jt * 16 + (l & 15);
        int slot = cb2 ^ (jrow & 7);
        bf16x8 bfrag = *(const bf16x8*)&Bl[jrow * 64 + slot * 8];
        acc[jt] = __builtin_amdgcn_mfma_f32_16x16x32_bf16(afrag, bfrag, acc[jt], 0, 0, 0);
      }
    }
    __syncthreads();
  }
  float* op = out + (size_t)n * MM * 256;
  const int mrb = m0 + w * 16 + ((l >> 4) << 2);
  #pragma unroll
  for (int jt = 0; jt < 16; ++jt) {
    int jcol = jt * 16 + (l & 15);
    float bias = bb[n * 256 + jcol];
    #pragma unroll
    for (int r = 0; r < 4; ++r)
      op[(size_t)(mrb + r) * 256 + jcol] = acc[jt][r] + bias;
  }
}

// ---------------------------------------------------------------------------
extern "C" void kernel_launch(void* const* d_in, const int* in_sizes, int n_in,
                              void* d_out, int out_size, void* d_ws, size_t ws_size,
                              hipStream_t stream) {
  (void)in_sizes; (void)n_in; (void)out_size;
  const float* x  = (const float*)d_in[0];
  const float* Wq = (const float*)d_in[1];
  const float* bq = (const float*)d_in[2];
  const float* Wk = (const float*)d_in[3];
  const float* bk = (const float*)d_in[4];
  const float* Wv = (const float*)d_in[5];
  const float* bv = (const float*)d_in[6];
  float* out = (float*)d_out;

  int spb = 128;
  while (spb > 1) {
    size_t need = ((size_t)2 * spb * (65536 + 256) + 2 * 65536 + 512 + 512 + 65536) * 4
                + (size_t)2 * 65536 * 2;
    if (need <= ws_size) break;
    spb >>= 1;
  }
  float* wsf   = (float*)d_ws;
  float* gpart = wsf;
  float* spart = gpart + (size_t)2 * spb * 65536;
  float* G     = spart + (size_t)2 * spb * 256;
  float* sv    = G + 2 * 65536;
  float* bb    = sv + 512;
  float* WkT   = bb + 512;
  unsigned short* Bm = (unsigned short*)(WkT + 65536);
  const int Mc = MM / spb;

  gram_kernel<<<dim3(2 * spb), dim3(512), 0, stream>>>(x, gpart, spart, Mc, spb);
  reduce_kernel<<<dim3(770), dim3(256), 0, stream>>>(gpart, spart, Wk, G, sv, WkT, spb);
  chain_kernel<<<dim3(256), dim3(256), 0, stream>>>(G, sv, WkT, Wq, bq, bk, bv, Wv, Bm, bb);
  out_kernel<<<dim3(1024), dim3(256), 0, stream>>>(x, Bm, bb, out);
}

// Round 6
// 84.295 us; speedup vs baseline: 1.6943x; 1.4253x over previous
//
#include <hip/hip_runtime.h>
#include <hip/hip_bf16.h>

#define CCH 256
#define MM  32768

typedef float    f32x4  __attribute__((ext_vector_type(4)));
typedef _Float16 f16x8  __attribute__((ext_vector_type(8)));
typedef short    bf16x8 __attribute__((ext_vector_type(8)));

__device__ inline unsigned short f2bf(float f) {
  union { float f; unsigned int u; } v; v.f = f;
  unsigned int u = v.u;
  unsigned int r = (u + 0x7fffu + ((u >> 16) & 1u)) >> 16;
  return (unsigned short)r;
}

// ---------------------------------------------------------------------------
// K1: split-K Gram  G_partial = X_chunk * X_chunk^T  (fp16 two-term split)
// Partials stored UPPER-TRIANGLE ONLY (G symmetric) -> half the write traffic.
// ---------------------------------------------------------------------------
__global__ __launch_bounds__(512) void gram_kernel(const float* __restrict__ x,
    float* __restrict__ gpart, float* __restrict__ spart, int Mc, int spb) {
  __shared__ _Float16 hiL[CCH * 32];
  __shared__ _Float16 loL[CCH * 32];
  const int t = threadIdx.x;
  const int b = blockIdx.x;
  const int n = b / spb, ks = b % spb;
  const float* X = x + (size_t)n * CCH * MM + (size_t)ks * Mc;
  const int c = t >> 1, mo = (t & 1) << 4;
  const float* px = X + (size_t)c * MM + mo;
  const int stages = Mc >> 5;
  const int l = t & 63, w = t >> 6;
  const int i0 = w << 1;

  f32x4 acc[2][16];
  #pragma unroll
  for (int ii = 0; ii < 2; ++ii)
    #pragma unroll
    for (int jt = 0; jt < 16; ++jt)
      acc[ii][jt] = (f32x4){0.f, 0.f, 0.f, 0.f};

  float4 p0 = *(const float4*)(px + 0);
  float4 p1 = *(const float4*)(px + 4);
  float4 p2 = *(const float4*)(px + 8);
  float4 p3 = *(const float4*)(px + 12);
  float ssum = 0.f;

  const int kb0 = (t & 1) * 2;
  const int sw  = (c >> 1) & 3;
  _Float16* hd0 = &hiL[c * 32 + ((kb0 + 0) ^ sw) * 8];
  _Float16* hd1 = &hiL[c * 32 + ((kb0 + 1) ^ sw) * 8];
  _Float16* ld0 = &loL[c * 32 + ((kb0 + 0) ^ sw) * 8];
  _Float16* ld1 = &loL[c * 32 + ((kb0 + 1) ^ sw) * 8];

  for (int s = 0; s < stages; ++s) {
    float fv[16];
    fv[0] = p0.x; fv[1] = p0.y; fv[2]  = p0.z; fv[3]  = p0.w;
    fv[4] = p1.x; fv[5] = p1.y; fv[6]  = p1.z; fv[7]  = p1.w;
    fv[8] = p2.x; fv[9] = p2.y; fv[10] = p2.z; fv[11] = p2.w;
    fv[12] = p3.x; fv[13] = p3.y; fv[14] = p3.z; fv[15] = p3.w;
    f16x8 h0, h1, lo0, lo1;
    #pragma unroll
    for (int e = 0; e < 8; ++e) {
      float a = fv[e]; ssum += a;
      _Float16 hh = (_Float16)a;
      h0[e] = hh; lo0[e] = (_Float16)(a - (float)hh);
    }
    #pragma unroll
    for (int e = 0; e < 8; ++e) {
      float a = fv[8 + e]; ssum += a;
      _Float16 hh = (_Float16)a;
      h1[e] = hh; lo1[e] = (_Float16)(a - (float)hh);
    }
    *(f16x8*)hd0 = h0;  *(f16x8*)hd1 = h1;
    *(f16x8*)ld0 = lo0; *(f16x8*)ld1 = lo1;
    if (s + 1 < stages) {
      const float* pn = px + (size_t)(s + 1) * 32;
      p0 = *(const float4*)(pn + 0);
      p1 = *(const float4*)(pn + 4);
      p2 = *(const float4*)(pn + 8);
      p3 = *(const float4*)(pn + 12);
    }
    __syncthreads();
    f16x8 Ahi[2], Alo[2];
    #pragma unroll
    for (int ii = 0; ii < 2; ++ii) {
      int cr = (i0 + ii) * 16 + (l & 15);
      int sl = (l >> 4) ^ ((cr >> 1) & 3);
      int idx = cr * 32 + sl * 8;
      Ahi[ii] = *(const f16x8*)&hiL[idx];
      Alo[ii] = *(const f16x8*)&loL[idx];
    }
    #pragma unroll
    for (int jt = 0; jt < 16; ++jt) {
      int cr = jt * 16 + (l & 15);
      int sl = (l >> 4) ^ ((cr >> 1) & 3);
      int idx = cr * 32 + sl * 8;
      f16x8 Bhi = *(const f16x8*)&hiL[idx];
      f16x8 Blo = *(const f16x8*)&loL[idx];
      #pragma unroll
      for (int ii = 0; ii < 2; ++ii) {
        acc[ii][jt] = __builtin_amdgcn_mfma_f32_16x16x32_f16(Ahi[ii], Bhi, acc[ii][jt], 0, 0, 0);
        acc[ii][jt] = __builtin_amdgcn_mfma_f32_16x16x32_f16(Ahi[ii], Blo, acc[ii][jt], 0, 0, 0);
        acc[ii][jt] = __builtin_amdgcn_mfma_f32_16x16x32_f16(Alo[ii], Bhi, acc[ii][jt], 0, 0, 0);
      }
    }
    __syncthreads();
  }
  float* gp = gpart + ((size_t)n * spb + ks) * 65536;
  #pragma unroll
  for (int ii = 0; ii < 2; ++ii)
    #pragma unroll
    for (int jt = 0; jt < 16; ++jt) {
      int col = jt * 16 + (l & 15);
      int rb  = (i0 + ii) * 16 + ((l >> 4) << 2);
      #pragma unroll
      for (int r = 0; r < 4; ++r)
        if (col >= rb + r)                       // upper triangle only
          gp[(rb + r) * 256 + col] = acc[ii][jt][r];
    }
  ssum += __shfl_xor(ssum, 1);
  if ((t & 1) == 0) spart[((size_t)n * spb + ks) * 256 + c] = ssum;
}

// ---------------------------------------------------------------------------
// K1b: reduce upper-tri partials -> full G (mirrored), s, WkT.
// ---------------------------------------------------------------------------
__global__ __launch_bounds__(256) void reduce_kernel(const float* __restrict__ gpart,
    const float* __restrict__ spart, const float* __restrict__ Wk,
    float* __restrict__ G, float* __restrict__ sv, float* __restrict__ WkT,
    int spb) {
  const int b = blockIdx.x, t = threadIdx.x;
  if (b < 512) {
    const int n = b >> 8, i = b & 255;
    if (t >= i) {
      const float* p = gpart + (size_t)n * spb * 65536 + i * 256 + t;
      float s = 0.f;
      #pragma unroll 8
      for (int k = 0; k < spb; ++k) s += p[(size_t)k * 65536];
      float* Gn = G + (size_t)n * 65536;
      Gn[i * 256 + t] = s;
      if (t > i) Gn[t * 256 + i] = s;
    }
  } else if (b < 514) {
    int r = (b - 512) * 256 + t;
    int n = r >> 8, cc = r & 255;
    const float* p = spart + (size_t)n * spb * 256 + cc;
    float s = 0.f;
    #pragma unroll 8
    for (int k = 0; k < spb; ++k) s += p[k * 256];
    sv[r] = s;
  } else {
    int c = b - 514;
    WkT[c * 256 + t] = Wk[t * 256 + c];
  }
}

// ---------------------------------------------------------------------------
// K2 (fused chain, corrected wave-split): block = 2 rows (j0,j0+1), batch n.
// Wave w owns c in [64w,64w+64); lane l covers OUTPUTS o=4l..4l+3 via one
// float4 load per c. Every wave writes ALL 256 output slots of its part[w]
// plane -> cross-wave combine is complete (the R5 bug was partial coverage).
// ---------------------------------------------------------------------------
__global__ __launch_bounds__(256) void chain_kernel(const float* __restrict__ G,
    const float* __restrict__ sv_g, const float* __restrict__ WkT,
    const float* __restrict__ Wq, const float* __restrict__ bq,
    const float* __restrict__ bk, const float* __restrict__ bv,
    const float* __restrict__ Wv,
    unsigned short* __restrict__ Bm, float* __restrict__ bb) {
  __shared__ float wqL[2][256], sL[256], t1L[2][256], attL[2][256];
  __shared__ float part[4][3][256];
  __shared__ float red[4][2];
  const int t = threadIdx.x;
  const int l = t & 63, w = t >> 6;
  const int n = blockIdx.x >> 7;
  const int j0 = (blockIdx.x & 127) << 1;
  const int c0 = w << 6;                 // this wave's c-range
  const int o4 = l << 2;                 // this thread's 4 output columns
  const float* Gn = G + (size_t)n * 65536;

  wqL[0][t] = Wq[(size_t)j0 * 256 + t];
  wqL[1][t] = Wq[(size_t)(j0 + 1) * 256 + t];
  sL[t]     = sv_g[n * 256 + t];
  __syncthreads();

  // z2[r] = wq_r . s
  float p0 = wqL[0][t] * sL[t];
  float p1 = wqL[1][t] * sL[t];
  #pragma unroll
  for (int o = 1; o < 64; o <<= 1) { p0 += __shfl_xor(p0, o); p1 += __shfl_xor(p1, o); }
  if (l == 0) { red[w][0] = p0; red[w][1] = p1; }
  __syncthreads();
  const float z2_0 = red[0][0] + red[1][0] + red[2][0] + red[3][0];
  const float z2_1 = red[0][1] + red[1][1] + red[2][1] + red[3][1];

  // phase 1: T1 partials (wave-split over c, float4 over outputs)
  {
    f32x4 a0 = (f32x4){0.f,0.f,0.f,0.f}, a1 = a0;
    #pragma unroll 16
    for (int cg = 0; cg < 64; ++cg) {
      int c = c0 + cg;
      f32x4 g = *(const f32x4*)(Gn + (size_t)c * 256 + o4);
      float w0 = wqL[0][c], w1 = wqL[1][c];    // LDS broadcast
      a0 += w0 * g; a1 += w1 * g;
    }
    *(f32x4*)&part[w][0][o4] = a0;
    *(f32x4*)&part[w][1][o4] = a1;
  }
  __syncthreads();
  t1L[0][t] = part[0][0][t] + part[1][0][t] + part[2][0][t] + part[3][0][t];
  t1L[1][t] = part[0][1][t] + part[1][1][t] + part[2][1][t] + part[3][1][t];
  __syncthreads();

  // phase 2: S partials
  {
    f32x4 x0 = (f32x4){0.f,0.f,0.f,0.f}, x1 = x0, x2 = x0;
    #pragma unroll 16
    for (int cg = 0; cg < 64; ++cg) {
      int c = c0 + cg;
      f32x4 k4 = *(const f32x4*)(WkT + (size_t)c * 256 + o4);
      float t10 = t1L[0][c], t11 = t1L[1][c], sc = sL[c];
      x0 += t10 * k4; x1 += t11 * k4; x2 += sc * k4;
    }
    *(f32x4*)&part[w][0][o4] = x0;
    *(f32x4*)&part[w][1][o4] = x1;
    *(f32x4*)&part[w][2][o4] = x2;
  }
  __syncthreads();
  float b0 = part[0][0][t] + part[1][0][t] + part[2][0][t] + part[3][0][t];
  float b1 = part[0][1][t] + part[1][1][t] + part[2][1][t] + part[3][1][t];
  float aa = part[0][2][t] + part[1][2][t] + part[2][2][t] + part[3][2][t];

  const float bq0 = bq[j0], bq1 = bq[j0 + 1];
  const float bkt = bk[t];
  float S0 = b0 + bq0 * aa + (z2_0 + 32768.0f * bq0) * bkt;
  float S1 = b1 + bq1 * aa + (z2_1 + 32768.0f * bq1) * bkt;

  // softmax over t
  float m0 = S0, m1 = S1;
  #pragma unroll
  for (int o = 1; o < 64; o <<= 1) {
    m0 = fmaxf(m0, __shfl_xor(m0, o)); m1 = fmaxf(m1, __shfl_xor(m1, o));
  }
  __syncthreads();
  if (l == 0) { red[w][0] = m0; red[w][1] = m1; }
  __syncthreads();
  m0 = fmaxf(fmaxf(red[0][0], red[1][0]), fmaxf(red[2][0], red[3][0]));
  m1 = fmaxf(fmaxf(red[0][1], red[1][1]), fmaxf(red[2][1], red[3][1]));
  float e0 = expf(S0 - m0), e1 = expf(S1 - m1);
  float q0 = e0, q1 = e1;
  #pragma unroll
  for (int o = 1; o < 64; o <<= 1) { q0 += __shfl_xor(q0, o); q1 += __shfl_xor(q1, o); }
  __syncthreads();
  if (l == 0) { red[w][0] = q0; red[w][1] = q1; }
  __syncthreads();
  const float i0 = 1.0f / (red[0][0] + red[1][0] + red[2][0] + red[3][0]);
  const float i1 = 1.0f / (red[0][1] + red[1][1] + red[2][1] + red[3][1]);
  const float at0 = e0 * i0, at1 = e1 * i1;
  attL[0][t] = at0;
  attL[1][t] = at1;

  // bb[r] = att_r . bv
  const float bvt = bv[t];
  float d0 = at0 * bvt, d1 = at1 * bvt;
  #pragma unroll
  for (int o = 1; o < 64; o <<= 1) { d0 += __shfl_xor(d0, o); d1 += __shfl_xor(d1, o); }
  __syncthreads();
  if (l == 0) { red[w][0] = d0; red[w][1] = d1; }
  __syncthreads();                        // also publishes attL
  if (t < 2) bb[n * 256 + j0 + t] = red[0][t] + red[1][t] + red[2][t] + red[3][t];

  // phase 3: Bm partials
  {
    f32x4 v0 = (f32x4){0.f,0.f,0.f,0.f}, v1 = v0;
    #pragma unroll 16
    for (int cg = 0; cg < 64; ++cg) {
      int c = c0 + cg;
      f32x4 wv = *(const f32x4*)(Wv + (size_t)c * 256 + o4);
      float A0 = attL[0][c], A1 = attL[1][c];
      v0 += A0 * wv; v1 += A1 * wv;
    }
    *(f32x4*)&part[w][0][o4] = v0;
    *(f32x4*)&part[w][1][o4] = v1;
  }
  __syncthreads();
  float v0 = part[0][0][t] + part[1][0][t] + part[2][0][t] + part[3][0][t];
  float v1 = part[0][1][t] + part[1][1][t] + part[2][1][t] + part[3][1][t];
  unsigned short* bmb = Bm + ((size_t)(n * 256 + j0)) * 256;
  bmb[t]       = f2bf(v0);
  bmb[256 + t] = f2bf(v1);
}

// ---------------------------------------------------------------------------
// K3: out[n][m][j] = sum_c Bmat[j][c] * X[c][m] + bb[j]   (bf16 MFMA)
// ---------------------------------------------------------------------------
__global__ __launch_bounds__(256) void out_kernel(const float* __restrict__ x,
    const unsigned short* __restrict__ Bm, const float* __restrict__ bb,
    float* __restrict__ out) {
  __shared__ unsigned short Bl[256 * 64];
  const int t = threadIdx.x;
  const int b = blockIdx.x;
  const int n = b >> 9, mb = b & 511;
  const int m0 = mb << 6;
  const int l = t & 63, w = t >> 6;
  f32x4 acc[16];
  #pragma unroll
  for (int jt = 0; jt < 16; ++jt) acc[jt] = (f32x4){0.f, 0.f, 0.f, 0.f};
  const unsigned short* Bmn = Bm + (size_t)n * 65536;
  const float* xn = x + (size_t)n * CCH * MM;
  const int mA = m0 + w * 16 + (l & 15);
  for (int ch = 0; ch < 4; ++ch) {
    #pragma unroll
    for (int it = 0; it < 8; ++it) {
      int i = it * 256 + t;
      int j = i >> 3, cb = i & 7;
      uint4 v = *(const uint4*)(Bmn + (size_t)j * 256 + ch * 64 + cb * 8);
      int slot = cb ^ (j & 7);
      *(uint4*)&Bl[j * 64 + slot * 8] = v;
    }
    __syncthreads();
    #pragma unroll
    for (int kk = 0; kk < 2; ++kk) {
      int cbase = ch * 64 + kk * 32 + (l >> 4) * 8;
      const float* xp = xn + (size_t)cbase * MM + mA;
      bf16x8 afrag;
      #pragma unroll
      for (int jj = 0; jj < 8; ++jj) {
        float v = xp[(size_t)jj * MM];
        afrag[jj] = (short)f2bf(v);
      }
      int cb2 = kk * 4 + (l >> 4);
      #pragma unroll
      for (int jt = 0; jt < 16; ++jt) {
        int jrow = jt * 16 + (l & 15);
        int slot = cb2 ^ (jrow & 7);
        bf16x8 bfrag = *(const bf16x8*)&Bl[jrow * 64 + slot * 8];
        acc[jt] = __builtin_amdgcn_mfma_f32_16x16x32_bf16(afrag, bfrag, acc[jt], 0, 0, 0);
      }
    }
    __syncthreads();
  }
  float* op = out + (size_t)n * MM * 256;
  const int mrb = m0 + w * 16 + ((l >> 4) << 2);
  #pragma unroll
  for (int jt = 0; jt < 16; ++jt) {
    int jcol = jt * 16 + (l & 15);
    float bias = bb[n * 256 + jcol];
    #pragma unroll
    for (int r = 0; r < 4; ++r)
      op[(size_t)(mrb + r) * 256 + jcol] = acc[jt][r] + bias;
  }
}

// ---------------------------------------------------------------------------
extern "C" void kernel_launch(void* const* d_in, const int* in_sizes, int n_in,
                              void* d_out, int out_size, void* d_ws, size_t ws_size,
                              hipStream_t stream) {
  (void)in_sizes; (void)n_in; (void)out_size;
  const float* x  = (const float*)d_in[0];
  const float* Wq = (const float*)d_in[1];
  const float* bq = (const float*)d_in[2];
  const float* Wk = (const float*)d_in[3];
  const float* bk = (const float*)d_in[4];
  const float* Wv = (const float*)d_in[5];
  const float* bv = (const float*)d_in[6];
  float* out = (float*)d_out;

  int spb = 128;
  while (spb > 1) {
    size_t need = ((size_t)2 * spb * (65536 + 256) + 2 * 65536 + 512 + 512 + 65536) * 4
                + (size_t)2 * 65536 * 2;
    if (need <= ws_size) break;
    spb >>= 1;
  }
  float* wsf   = (float*)d_ws;
  float* gpart = wsf;
  float* spart = gpart + (size_t)2 * spb * 65536;
  float* G     = spart + (size_t)2 * spb * 256;
  float* sv    = G + 2 * 65536;
  float* bb    = sv + 512;
  float* WkT   = bb + 512;
  unsigned short* Bm = (unsigned short*)(WkT + 65536);
  const int Mc = MM / spb;

  gram_kernel<<<dim3(2 * spb), dim3(512), 0, stream>>>(x, gpart, spart, Mc, spb);
  reduce_kernel<<<dim3(770), dim3(256), 0, stream>>>(gpart, spart, Wk, G, sv, WkT, spb);
  chain_kernel<<<dim3(256), dim3(256), 0, stream>>>(G, sv, WkT, Wq, bq, bk, bv, Wv, Bm, bb);
  out_kernel<<<dim3(1024), dim3(256), 0, stream>>>(x, Bm, bb, out);
}